// Round 1
// baseline (2414.642 us; speedup 1.0000x reference)
//
#include <hip/hip_runtime.h>

#define RESV 32
#define R3 (RESV * RESV * RESV)

// ---------------- K1: per-batch coordinate sums (for mean) ----------------
__global__ void k_sums(const float* __restrict__ coords, float* __restrict__ ws_sums, int N) {
    const int b = blockIdx.y;
    const float* cb = coords + (size_t)b * 3 * N;
    float sx = 0.f, sy = 0.f, sz = 0.f;
    for (int n = blockIdx.x * blockDim.x + threadIdx.x; n < N; n += gridDim.x * blockDim.x) {
        sx += cb[n];
        sy += cb[N + n];
        sz += cb[2 * N + n];
    }
    for (int off = 32; off > 0; off >>= 1) {
        sx += __shfl_down(sx, off);
        sy += __shfl_down(sy, off);
        sz += __shfl_down(sz, off);
    }
    __shared__ float red[3][4];
    const int lane = threadIdx.x & 63;
    const int wv   = threadIdx.x >> 6;
    if (lane == 0) { red[0][wv] = sx; red[1][wv] = sy; red[2][wv] = sz; }
    __syncthreads();
    if (threadIdx.x == 0) {
        float tx = 0.f, ty = 0.f, tz = 0.f;
        const int nw = blockDim.x >> 6;
        for (int w = 0; w < nw; ++w) { tx += red[0][w]; ty += red[1][w]; tz += red[2][w]; }
        atomicAdd(&ws_sums[b * 3 + 0], tx);
        atomicAdd(&ws_sums[b * 3 + 1], ty);
        atomicAdd(&ws_sums[b * 3 + 2], tz);
    }
}

// ---------------- K2: per-batch max radius ----------------
__global__ void k_maxrad(const float* __restrict__ coords, const float* __restrict__ ws_sums,
                         unsigned int* __restrict__ ws_max, int N) {
    const int b = blockIdx.y;
    const float invN = 1.0f / (float)N;
    const float mx = ws_sums[b * 3 + 0] * invN;
    const float my = ws_sums[b * 3 + 1] * invN;
    const float mz = ws_sums[b * 3 + 2] * invN;
    const float* cb = coords + (size_t)b * 3 * N;
    float r = 0.f;
    for (int n = blockIdx.x * blockDim.x + threadIdx.x; n < N; n += gridDim.x * blockDim.x) {
        const float dx = cb[n] - mx;
        const float dy = cb[N + n] - my;
        const float dz = cb[2 * N + n] - mz;
        r = fmaxf(r, sqrtf(dx * dx + dy * dy + dz * dz));
    }
    for (int off = 32; off > 0; off >>= 1) r = fmaxf(r, __shfl_down(r, off));
    __shared__ float red[4];
    const int lane = threadIdx.x & 63;
    const int wv   = threadIdx.x >> 6;
    if (lane == 0) red[wv] = r;
    __syncthreads();
    if (threadIdx.x == 0) {
        const int nw = blockDim.x >> 6;
        float t = 0.f;
        for (int w = 0; w < nw; ++w) t = fmaxf(t, red[w]);
        atomicMax(&ws_max[b], __float_as_uint(t));  // radii >= 0: uint order == float order
    }
}

// ---------------- K3: per-point norm coords, voxel idx, counts ----------------
__global__ void k_points(const float* __restrict__ coords, const float* __restrict__ ws_sums,
                         const unsigned int* __restrict__ ws_max,
                         float* __restrict__ norm_out, int* __restrict__ idx_ws,
                         float* __restrict__ cnt_ws, int N) {
    const int b = blockIdx.y;
    const int n = blockIdx.x * blockDim.x + threadIdx.x;
    if (n >= N) return;
    const float invN  = 1.0f / (float)N;
    const float scale = 2.0f * __uint_as_float(ws_max[b]);
    const float* cb = coords + (size_t)b * 3 * N;
    float* nb = norm_out + (size_t)b * 3 * N;

    int flat = 0;
#pragma unroll
    for (int d = 0; d < 3; ++d) {
        const float mean = ws_sums[b * 3 + d] * invN;
        float nc = (cb[d * N + n] - mean) / scale + 0.5f;
        nc = fminf(fmaxf(nc * (float)RESV, 0.0f), (float)(RESV - 1));
        nb[d * N + n] = nc;
        flat = flat * RESV + (int)rintf(nc);  // round half-to-even, matches np/jnp
    }
    idx_ws[b * N + n] = flat;
    atomicAdd(&cnt_ws[b * R3 + flat], 1.0f);
}

// ---------------- K3b: reciprocal of counts ----------------
__global__ void k_recip(const float* __restrict__ cnt, float* __restrict__ recip, int total) {
    const int i = blockIdx.x * blockDim.x + threadIdx.x;
    if (i < total) recip[i] = 1.0f / fmaxf(cnt[i], 1.0f);
}

// ---------------- K4: scatter features (pre-scaled by 1/cnt) ----------------
__global__ void k_scatter(const float* __restrict__ feats, const int* __restrict__ idx_ws,
                          const float* __restrict__ recip, float* __restrict__ grid,
                          int N, int C) {
    const int bc = blockIdx.y;  // b*C + c
    const int n  = blockIdx.x * blockDim.x + threadIdx.x;
    if (n >= N) return;
    const int b    = bc / C;
    const int flat = idx_ws[b * N + n];
    const float f  = feats[(size_t)bc * N + n];
    const float r  = recip[b * R3 + flat];
    atomicAdd(&grid[(size_t)bc * R3 + flat], f * r);
}

extern "C" void kernel_launch(void* const* d_in, const int* in_sizes, int n_in,
                              void* d_out, int out_size, void* d_ws, size_t ws_size,
                              hipStream_t stream) {
    const float* feats  = (const float*)d_in[0];
    const float* coords = (const float*)d_in[1];

    // Derive dims: in_sizes[0]=B*C*N, in_sizes[1]=B*3*N, out_size=B*C*R3 + B*3*N
    const long long s0 = in_sizes[0], s1 = in_sizes[1];
    const int BC = (int)(((long long)out_size - s1) / R3);      // B*C
    const int N  = (int)(s0 / BC);
    const int B  = (int)(s1 / (3LL * N));
    const int C  = BC / B;

    float* out_grid = (float*)d_out;                 // [B, C, R3]
    float* out_norm = out_grid + (size_t)BC * R3;    // [B, 3, N]

    // ws layout (floats): [0,24) sums, [32,40) max bits, [64, 64+B*R3) counts,
    // then recips, then idx (ints)
    float*        ws_sums = (float*)d_ws;
    unsigned int* ws_max  = (unsigned int*)((float*)d_ws + 32);
    float*        ws_cnt  = (float*)d_ws + 64;
    float*        ws_rcp  = ws_cnt + (size_t)B * R3;
    int*          ws_idx  = (int*)(ws_rcp + (size_t)B * R3);

    // Zero accumulators (harness does not re-zero between replays)
    hipMemsetAsync(d_ws, 0, (64 + (size_t)B * R3) * sizeof(float), stream);
    hipMemsetAsync(out_grid, 0, (size_t)BC * R3 * sizeof(float), stream);

    const int BLK = 256;
    dim3 gRed(32, B);
    k_sums<<<gRed, BLK, 0, stream>>>(coords, ws_sums, N);
    k_maxrad<<<gRed, BLK, 0, stream>>>(coords, ws_sums, ws_max, N);

    dim3 gPts((N + BLK - 1) / BLK, B);
    k_points<<<gPts, BLK, 0, stream>>>(coords, ws_sums, ws_max, out_norm, ws_idx, ws_cnt, N);

    const int tot = B * R3;
    k_recip<<<(tot + BLK - 1) / BLK, BLK, 0, stream>>>(ws_cnt, ws_rcp, tot);

    dim3 gSc((N + BLK - 1) / BLK, BC);
    k_scatter<<<gSc, BLK, 0, stream>>>(feats, ws_idx, ws_rcp, out_grid, N, C);
}

// Round 2
// 362.224 us; speedup vs baseline: 6.6662x; 6.6662x over previous
//
#include <hip/hip_runtime.h>

#define RESV 32
#define R3 (RESV * RESV * RESV)

// ---------------- K1: per-batch coordinate sums (for mean) ----------------
__global__ void k_sums(const float* __restrict__ coords, float* __restrict__ ws_sums, int N) {
    const int b = blockIdx.y;
    const float* cb = coords + (size_t)b * 3 * N;
    float sx = 0.f, sy = 0.f, sz = 0.f;
    for (int n = blockIdx.x * blockDim.x + threadIdx.x; n < N; n += gridDim.x * blockDim.x) {
        sx += cb[n];
        sy += cb[N + n];
        sz += cb[2 * N + n];
    }
    for (int off = 32; off > 0; off >>= 1) {
        sx += __shfl_down(sx, off);
        sy += __shfl_down(sy, off);
        sz += __shfl_down(sz, off);
    }
    __shared__ float red[3][4];
    const int lane = threadIdx.x & 63;
    const int wv   = threadIdx.x >> 6;
    if (lane == 0) { red[0][wv] = sx; red[1][wv] = sy; red[2][wv] = sz; }
    __syncthreads();
    if (threadIdx.x == 0) {
        float tx = 0.f, ty = 0.f, tz = 0.f;
        const int nw = blockDim.x >> 6;
        for (int w = 0; w < nw; ++w) { tx += red[0][w]; ty += red[1][w]; tz += red[2][w]; }
        atomicAdd(&ws_sums[b * 3 + 0], tx);
        atomicAdd(&ws_sums[b * 3 + 1], ty);
        atomicAdd(&ws_sums[b * 3 + 2], tz);
    }
}

// ---------------- K2: per-batch max radius ----------------
__global__ void k_maxrad(const float* __restrict__ coords, const float* __restrict__ ws_sums,
                         unsigned int* __restrict__ ws_max, int N) {
    const int b = blockIdx.y;
    const float invN = 1.0f / (float)N;
    const float mx = ws_sums[b * 3 + 0] * invN;
    const float my = ws_sums[b * 3 + 1] * invN;
    const float mz = ws_sums[b * 3 + 2] * invN;
    const float* cb = coords + (size_t)b * 3 * N;
    float r = 0.f;
    for (int n = blockIdx.x * blockDim.x + threadIdx.x; n < N; n += gridDim.x * blockDim.x) {
        const float dx = cb[n] - mx;
        const float dy = cb[N + n] - my;
        const float dz = cb[2 * N + n] - mz;
        r = fmaxf(r, sqrtf(dx * dx + dy * dy + dz * dz));
    }
    for (int off = 32; off > 0; off >>= 1) r = fmaxf(r, __shfl_down(r, off));
    __shared__ float red[4];
    const int lane = threadIdx.x & 63;
    const int wv   = threadIdx.x >> 6;
    if (lane == 0) red[wv] = r;
    __syncthreads();
    if (threadIdx.x == 0) {
        const int nw = blockDim.x >> 6;
        float t = 0.f;
        for (int w = 0; w < nw; ++w) t = fmaxf(t, red[w]);
        atomicMax(&ws_max[b], __float_as_uint(t));  // radii >= 0: uint order == float order
    }
}

// ---------------- K3: per-point norm coords, voxel idx, counts ----------------
__global__ void k_points(const float* __restrict__ coords, const float* __restrict__ ws_sums,
                         const unsigned int* __restrict__ ws_max,
                         float* __restrict__ norm_out, int* __restrict__ idx_ws,
                         float* __restrict__ cnt_ws, int N) {
    const int b = blockIdx.y;
    const int n = blockIdx.x * blockDim.x + threadIdx.x;
    if (n >= N) return;
    const float invN  = 1.0f / (float)N;
    const float scale = 2.0f * __uint_as_float(ws_max[b]);
    const float* cb = coords + (size_t)b * 3 * N;
    float* nb = norm_out + (size_t)b * 3 * N;

    int flat = 0;
#pragma unroll
    for (int d = 0; d < 3; ++d) {
        const float mean = ws_sums[b * 3 + d] * invN;
        float nc = (cb[d * N + n] - mean) / scale + 0.5f;
        nc = fminf(fmaxf(nc * (float)RESV, 0.0f), (float)(RESV - 1));
        nb[d * N + n] = nc;
        flat = flat * RESV + (int)rintf(nc);  // round half-to-even, matches np/jnp
    }
    idx_ws[b * N + n] = flat;
    atomicAdd(&cnt_ws[b * R3 + flat], 1.0f);
}

// ---------------- K3b: reciprocal of counts ----------------
__global__ void k_recip(const float* __restrict__ cnt, float* __restrict__ recip, int total) {
    const int i = blockIdx.x * blockDim.x + threadIdx.x;
    if (i < total) recip[i] = 1.0f / fmaxf(cnt[i], 1.0f);
}

// ---------------- K4: per-(b,c)-plane LDS accumulation, then one coalesced write ----
// One workgroup owns one 32^3 plane (32768 floats = 128 KB dynamic LDS).
// Feature row read is fully coalesced float4; accumulation is LDS atomics
// (random voxel targets -> ~2 lanes/bank, near conflict-free); output written
// once, non-atomic, fused with the 1/cnt normalization (sums-then-divide,
// matching the reference order).
__global__ __launch_bounds__(1024, 1) void k_scatter_lds(
        const float* __restrict__ feats, const int* __restrict__ idx_ws,
        const float* __restrict__ recip, float* __restrict__ grid, int N, int C) {
    extern __shared__ float acc[];  // R3 floats
    const int bc  = blockIdx.x;
    const int b   = bc / C;
    const int tid = threadIdx.x;

    // zero LDS plane (8 float4 stores per thread)
    for (int i = tid * 4; i < R3; i += blockDim.x * 4) {
        *(float4*)(acc + i) = make_float4(0.f, 0.f, 0.f, 0.f);
    }
    __syncthreads();

    const float* fb = feats  + (size_t)bc * N;
    const int*   ib = idx_ws + (size_t)b  * N;
    const int n4 = (N / 4) * 4;
    for (int n = tid * 4; n < n4; n += blockDim.x * 4) {
        const float4 f = *(const float4*)(fb + n);
        const int4  ix = *(const int4*)(ib + n);
        atomicAdd(&acc[ix.x], f.x);
        atomicAdd(&acc[ix.y], f.y);
        atomicAdd(&acc[ix.z], f.z);
        atomicAdd(&acc[ix.w], f.w);
    }
    for (int n = n4 + tid; n < N; n += blockDim.x) {
        atomicAdd(&acc[ib[n]], fb[n]);
    }
    __syncthreads();

    const float* rb = recip + (size_t)b * R3;  // L2-resident (shared across C blocks)
    float*       gb = grid  + (size_t)bc * R3;
    for (int i = tid * 4; i < R3; i += blockDim.x * 4) {
        const float4 a = *(const float4*)(acc + i);
        const float4 r = *(const float4*)(rb + i);
        *(float4*)(gb + i) = make_float4(a.x * r.x, a.y * r.y, a.z * r.z, a.w * r.w);
    }
}

extern "C" void kernel_launch(void* const* d_in, const int* in_sizes, int n_in,
                              void* d_out, int out_size, void* d_ws, size_t ws_size,
                              hipStream_t stream) {
    const float* feats  = (const float*)d_in[0];
    const float* coords = (const float*)d_in[1];

    // Derive dims: in_sizes[0]=B*C*N, in_sizes[1]=B*3*N, out_size=B*C*R3 + B*3*N
    const long long s0 = in_sizes[0], s1 = in_sizes[1];
    const int BC = (int)(((long long)out_size - s1) / R3);      // B*C
    const int N  = (int)(s0 / BC);
    const int B  = (int)(s1 / (3LL * N));
    const int C  = BC / B;

    float* out_grid = (float*)d_out;                 // [B, C, R3]
    float* out_norm = out_grid + (size_t)BC * R3;    // [B, 3, N]

    // ws layout (floats): [0,24) sums, [32,40) max bits, [64, 64+B*R3) counts,
    // then recips, then idx (ints)
    float*        ws_sums = (float*)d_ws;
    unsigned int* ws_max  = (unsigned int*)((float*)d_ws + 32);
    float*        ws_cnt  = (float*)d_ws + 64;
    float*        ws_rcp  = ws_cnt + (size_t)B * R3;
    int*          ws_idx  = (int*)(ws_rcp + (size_t)B * R3);

    // Zero accumulators (harness does not re-zero between replays).
    // out_grid needs no memset: k_scatter_lds writes every element.
    hipMemsetAsync(d_ws, 0, (64 + (size_t)B * R3) * sizeof(float), stream);

    const int BLK = 256;
    dim3 gRed(32, B);
    k_sums<<<gRed, BLK, 0, stream>>>(coords, ws_sums, N);
    k_maxrad<<<gRed, BLK, 0, stream>>>(coords, ws_sums, ws_max, N);

    dim3 gPts((N + BLK - 1) / BLK, B);
    k_points<<<gPts, BLK, 0, stream>>>(coords, ws_sums, ws_max, out_norm, ws_idx, ws_cnt, N);

    const int tot = B * R3;
    k_recip<<<(tot + BLK - 1) / BLK, BLK, 0, stream>>>(ws_cnt, ws_rcp, tot);

    // One block per (b,c) plane; 128 KB dynamic LDS.
    k_scatter_lds<<<dim3(BC), 1024, R3 * sizeof(float), stream>>>(
        feats, ws_idx, ws_rcp, out_grid, N, C);
}